// Round 1
// 789.658 us; speedup vs baseline: 1.0454x; 1.0454x over previous
//
#include <hip/hip_runtime.h>
#include <math.h>

#define N_NODES 100000
#define N_EDGES 1600000
#define IN_FEAT 512
#define HIDDEN 64
#define N_CLASSES 40
#define N_LAYERS 6

typedef _Float16 v8h __attribute__((ext_vector_type(8)));
typedef _Float16 v4h __attribute__((ext_vector_type(4)));
typedef float v4f __attribute__((ext_vector_type(4)));

// ---------------- graph preprocessing ----------------

__global__ void count_kernel(const int* __restrict__ dst, int* __restrict__ count) {
    int e = blockIdx.x * blockDim.x + threadIdx.x;
    if (e < N_EDGES) atomicAdd(&count[dst[e]], 1);
}

// scan over counts; also emits dinv = rsqrt(deg+1) (merged former dinv_kernel)
__global__ void scan1_kernel(const int* __restrict__ count, int* __restrict__ row_start,
                             int* __restrict__ bsum, float* __restrict__ dinv) {
    __shared__ int sm[256];
    int t = threadIdx.x;
    int g = blockIdx.x * 256 + t;
    int v = (g < N_NODES) ? count[g] : 0;
    if (g < N_NODES) dinv[g] = rsqrtf((float)(v + 1));  // +1 self loop
    sm[t] = v;
    __syncthreads();
    int x = v;
    for (int off = 1; off < 256; off <<= 1) {
        int y = (t >= off) ? sm[t - off] : 0;
        __syncthreads();
        x += y;
        sm[t] = x;
        __syncthreads();
    }
    if (g < N_NODES) row_start[g] = x - v;
    if (t == 255) bsum[blockIdx.x] = x;
}

__global__ void scan2_kernel(int* __restrict__ bsum, int nb) {
    __shared__ int sm[512];
    int t = threadIdx.x;
    int v = (t < nb) ? bsum[t] : 0;
    sm[t] = v;
    __syncthreads();
    int x = v;
    for (int off = 1; off < 512; off <<= 1) {
        int y = (t >= off) ? sm[t - off] : 0;
        __syncthreads();
        x += y;
        sm[t] = x;
        __syncthreads();
    }
    if (t < nb) bsum[t] = x - v;
}

__global__ void scan3_kernel(int* __restrict__ row_start, const int* __restrict__ bsum) {
    int g = blockIdx.x * 256 + threadIdx.x;
    if (g < N_NODES) row_start[g] += bsum[blockIdx.x];
    if (g == 0) row_start[N_NODES] = N_EDGES;
}

// CSR fill: src index only (norm folded into table rows). Reuses count as the
// cursor via atomicSub -> no cursor buffer, no second memset.
__global__ void fill_kernel(const int* __restrict__ src, const int* __restrict__ dst,
                            const int* __restrict__ row_start, int* __restrict__ count,
                            int* __restrict__ esrc) {
    int e = blockIdx.x * blockDim.x + threadIdx.x;
    if (e < N_EDGES) {
        int s = src[e], d = dst[e];
        int old = atomicSub(&count[d], 1);
        esrc[row_start[d] + old - 1] = s;
    }
}

// ---------------- weight prep: fp32 -> f16 transposed; zero table row ----------------

__global__ void prep_w(const float* __restrict__ W0, const float* __restrict__ W_rest,
                       const float* __restrict__ fcW,
                       _Float16* __restrict__ Wt0, _Float16* __restrict__ Wtr,
                       _Float16* __restrict__ fcWt, _Float16* __restrict__ tbl) {
    int i = blockIdx.x * 256 + threadIdx.x;
    if (i < IN_FEAT * 64) {
        int k = i >> 6, n = i & 63;
        Wt0[n * IN_FEAT + k] = (_Float16)W0[i];
    }
    if (i < (N_LAYERS - 1) * 64 * 64) {
        int l = i >> 12, k = (i >> 6) & 63, n = i & 63;
        Wtr[l * 4096 + n * 64 + k] = (_Float16)W_rest[i];
    }
    if (i < 48 * 64) {  // fcWt[n][k], pad n 40..47 with 0
        int n = i >> 6, k = i & 63;
        fcWt[i] = (n < N_CLASSES) ? (_Float16)fcW[k * N_CLASSES + n] : (_Float16)0.f;
    }
    if (i < 64) tbl[(size_t)N_NODES * 64 + i] = (_Float16)0.f;  // zero row for masked lanes
}

// ---------------- MFMA f16 GEMM: C[M x 64] = dinv[row] * (A[M x K] @ W[K x 64]) ----------------
// M-tile 128, BK=64 (single barrier pair per 64 K), 4 waves. LDS rows padded to
// 72 f16 (144 B): frag b128 reads 2-way bank aliased = free (m136).

#define LDP2 72

__global__ __launch_bounds__(256) void gemm_mfma(const void* __restrict__ Ap, int a_fp32, int K,
                                                 const _Float16* __restrict__ Wt,
                                                 const float* __restrict__ dinv,
                                                 _Float16* __restrict__ C, int M) {
    __shared__ _Float16 As[128][LDP2];
    __shared__ _Float16 Ws[64][LDP2];
    int t = threadIdx.x;
    int lane = t & 63, w = t >> 6;
    int quad = lane >> 4, l15 = lane & 15;
    int m0 = blockIdx.x * 128;
    v4f acc[2][4];
    #pragma unroll
    for (int u = 0; u < 2; u++)
        #pragma unroll
        for (int n = 0; n < 4; n++) acc[u][n] = (v4f){0.f, 0.f, 0.f, 0.f};

    for (int k0 = 0; k0 < K; k0 += 64) {
        if (a_fp32) {
            const float* A = (const float*)Ap;
            #pragma unroll
            for (int i = 0; i < 8; i++) {
                int idx = t + i * 256;            // 0..2047: 128 rows x 16 float4-segs
                int r = idx >> 4, seg = idx & 15;
                int gr = m0 + r;
                float4 v = make_float4(0.f, 0.f, 0.f, 0.f);
                if (gr < M) v = *(const float4*)(A + (size_t)gr * K + k0 + seg * 4);
                v4h h = {(_Float16)v.x, (_Float16)v.y, (_Float16)v.z, (_Float16)v.w};
                *(v4h*)&As[r][seg * 4] = h;
            }
        } else {
            const _Float16* A = (const _Float16*)Ap;
            #pragma unroll
            for (int i = 0; i < 4; i++) {
                int idx = t + i * 256;            // 0..1023: 128 rows x 8 uint4-segs
                int r = idx >> 3, seg = idx & 7;
                int gr = m0 + r;
                uint4 v = make_uint4(0u, 0u, 0u, 0u);
                if (gr < M) v = *(const uint4*)(A + (size_t)gr * K + k0 + seg * 8);
                *(uint4*)&As[r][seg * 8] = v;
            }
        }
        #pragma unroll
        for (int i = 0; i < 2; i++) {
            int idx = t + i * 256;                // 0..511: 64 rows x 8 uint4-segs
            int r = idx >> 3, seg = idx & 7;
            *(uint4*)&Ws[r][seg * 8] = *(const uint4*)(Wt + (size_t)r * K + k0 + seg * 8);
        }
        __syncthreads();
        #pragma unroll
        for (int kk = 0; kk < 2; kk++) {
            v8h a0 = *(v8h*)&As[w * 32 + l15][kk * 32 + quad * 8];
            v8h a1 = *(v8h*)&As[w * 32 + 16 + l15][kk * 32 + quad * 8];
            #pragma unroll
            for (int n = 0; n < 4; n++) {
                v8h b = *(v8h*)&Ws[n * 16 + l15][kk * 32 + quad * 8];
                acc[0][n] = __builtin_amdgcn_mfma_f32_16x16x32_f16(a0, b, acc[0][n], 0, 0, 0);
                acc[1][n] = __builtin_amdgcn_mfma_f32_16x16x32_f16(a1, b, acc[1][n], 0, 0, 0);
            }
        }
        __syncthreads();
    }
    #pragma unroll
    for (int u = 0; u < 2; u++)
        #pragma unroll
        for (int r = 0; r < 4; r++) {
            int gr = m0 + w * 32 + u * 16 + quad * 4 + r;
            if (gr < M) {
                float di = dinv[gr];  // broadcast across the 16 l15 lanes
                #pragma unroll
                for (int n = 0; n < 4; n++)
                    C[(size_t)gr * 64 + n * 16 + l15] = (_Float16)(acc[u][n][r] * di);
            }
        }
}

// ---------------- aggregation + bias + relu ----------------
// one wave per node; lane = g*8+j: group g takes edge base+g, lane loads a b128
// (8 f16 feats) -> 8 edges per gather instruction. Table rows are pre-scaled by
// dinv[src] (GEMM epilogue), so edges are weightless adds; lanes past the edge
// count gather the zero row (index N_NODES). Self-loop = group-0 init. Final
// result scaled once by dinv[node]. JK max deferred to the FC kernel.

__global__ __launch_bounds__(256) void agg_kernel(const _Float16* __restrict__ tbl,
                                                  const int* __restrict__ row_start,
                                                  const int* __restrict__ esrc,
                                                  const float* __restrict__ dinv,
                                                  const float* __restrict__ bias,
                                                  _Float16* __restrict__ h_out) {
    int wid = (blockIdx.x * blockDim.x + threadIdx.x) >> 6;
    if (wid >= N_NODES) return;
    int node = __builtin_amdgcn_readfirstlane(wid);
    int lane = threadIdx.x & 63;
    int g = lane >> 3, j = lane & 7;
    const v8h* t8 = (const v8h*)tbl;
    float di = dinv[node];
    int e0 = row_start[node], e1 = row_start[node + 1];

    float a[8];
    // self loop: table row already dinv[node]-scaled; keep only in group 0
    {
        v8h v = t8[(size_t)node * 8 + j];
        #pragma unroll
        for (int i = 0; i < 8; i++) a[i] = (g == 0) ? (float)v[i] : 0.f;
    }
    // pipelined weightless edge loop, 8 edges per round
    int e = e0 + g;
    int c = (e < e1) ? esrc[e] : N_NODES;
    for (int base = e0; base < e1; base += 8) {
        int en = base + 8 + g;
        int cn = (en < e1) ? esrc[en] : N_NODES;
        v8h v = t8[(size_t)c * 8 + j];
        #pragma unroll
        for (int i = 0; i < 8; i++) a[i] += (float)v[i];
        c = cn;
    }
    // combine the 8 lane-groups (xor over g bits 3,4,5)
    #pragma unroll
    for (int i = 0; i < 8; i++) {
        a[i] += __shfl_xor(a[i], 8, 64);
        a[i] += __shfl_xor(a[i], 16, 64);
        a[i] += __shfl_xor(a[i], 32, 64);
    }
    if (g == 0) {
        const float4* b4 = (const float4*)bias;
        float4 b0 = b4[j * 2], b1 = b4[j * 2 + 1];
        float bb[8] = {b0.x, b0.y, b0.z, b0.w, b1.x, b1.y, b1.z, b1.w};
        v8h hv;
        #pragma unroll
        for (int i = 0; i < 8; i++) hv[i] = (_Float16)fmaxf(a[i] * di + bb[i], 0.0f);
        ((v8h*)h_out)[(size_t)node * 8 + j] = hv;
    }
}

// ---------------- FC + log_softmax via MFMA; JK max fused into A-stage ----------------
// block 256 = 4 waves, M-tile 64 rows; N=48 (40 padded); K=64, single stage.

__global__ __launch_bounds__(256) void fc_mfma(const _Float16* __restrict__ hb,
                                               const _Float16* __restrict__ fcWt,
                                               const float* __restrict__ fcb,
                                               float* __restrict__ out, int M) {
    __shared__ _Float16 As[64][LDP2];
    __shared__ _Float16 Ws[48][LDP2];
    __shared__ float bs[48];
    int t = threadIdx.x;
    int lane = t & 63, w = t >> 6;
    int quad = lane >> 4, l15 = lane & 15;
    int m0 = blockIdx.x * 64;
    const size_t HST = (size_t)N_NODES * 64;

    if (t < 48) bs[t] = (t < N_CLASSES) ? fcb[t] : 0.0f;

    // A-stage with 6-layer elementwise max (values are post-relu >= 0)
    #pragma unroll
    for (int i = 0; i < 2; i++) {
        int idx = t + i * 256;                    // 0..511: 64 rows x 8 v8h-segs
        int r = idx >> 3, seg = idx & 7;
        int gr = m0 + r;
        v8h m = (v8h)(_Float16)0.f;
        if (gr < M) {
            size_t off = (size_t)gr * 64 + seg * 8;
            m = *(const v8h*)(hb + off);
            #pragma unroll
            for (int l = 1; l < N_LAYERS; l++) {
                v8h u = *(const v8h*)(hb + l * HST + off);
                #pragma unroll
                for (int k = 0; k < 8; k++) m[k] = (u[k] > m[k]) ? u[k] : m[k];
            }
        }
        *(v8h*)&As[r][seg * 8] = m;
    }
    #pragma unroll
    for (int i = 0; i < 2; i++) {
        int idx = t + i * 256;                    // 48 rows x 8 segs = 384
        if (idx < 384) {
            int r = idx >> 3, seg = idx & 7;
            *(uint4*)&Ws[r][seg * 8] = *(const uint4*)(fcWt + (size_t)r * 64 + seg * 8);
        }
    }
    __syncthreads();

    v4f acc[3];
    #pragma unroll
    for (int n = 0; n < 3; n++) acc[n] = (v4f){0.f, 0.f, 0.f, 0.f};
    #pragma unroll
    for (int kk = 0; kk < 2; kk++) {
        v8h a = *(v8h*)&As[w * 16 + l15][kk * 32 + quad * 8];
        #pragma unroll
        for (int n = 0; n < 3; n++) {
            v8h b = *(v8h*)&Ws[n * 16 + l15][kk * 32 + quad * 8];
            acc[n] = __builtin_amdgcn_mfma_f32_16x16x32_f16(a, b, acc[n], 0, 0, 0);
        }
    }

    float val[3][4];
    #pragma unroll
    for (int n = 0; n < 3; n++) {
        int col = n * 16 + l15;
        #pragma unroll
        for (int r = 0; r < 4; r++)
            val[n][r] = (col < N_CLASSES) ? acc[n][r] + bs[col] : -INFINITY;
    }
    #pragma unroll
    for (int r = 0; r < 4; r++) {
        float m = fmaxf(fmaxf(val[0][r], val[1][r]), val[2][r]);
        #pragma unroll
        for (int off = 8; off; off >>= 1) m = fmaxf(m, __shfl_xor(m, off, 64));
        float s = 0.f;
        #pragma unroll
        for (int n = 0; n < 3; n++)
            if (n * 16 + l15 < N_CLASSES) s += expf(val[n][r] - m);
        #pragma unroll
        for (int off = 8; off; off >>= 1) s += __shfl_xor(s, off, 64);
        float lse = m + logf(s);
        int gr = m0 + w * 16 + quad * 4 + r;
        if (gr < M) {
            #pragma unroll
            for (int n = 0; n < 3; n++) {
                int col = n * 16 + l15;
                if (col < N_CLASSES) out[(size_t)gr * N_CLASSES + col] = val[n][r] - lse;
            }
        }
    }
}

// ---------------- launch ----------------

extern "C" void kernel_launch(void* const* d_in, const int* in_sizes, int n_in,
                              void* d_out, int out_size, void* d_ws, size_t ws_size,
                              hipStream_t stream) {
    const float* x      = (const float*)d_in[0];
    const int*   ei     = (const int*)d_in[1];
    const float* W0     = (const float*)d_in[2];
    const float* b0     = (const float*)d_in[3];
    const float* W_rest = (const float*)d_in[4];
    const float* b_rest = (const float*)d_in[5];
    const float* fcW    = (const float*)d_in[6];
    const float* fcb    = (const float*)d_in[7];
    float* out = (float*)d_out;

    const int* src = ei;
    const int* dst = ei + N_EDGES;

    char* w = (char*)d_ws;
    auto alloc = [&](size_t bytes) -> void* {
        void* p = (void*)w;
        w += (bytes + 255) / 256 * 256;
        return p;
    };
    int*       count     = (int*)alloc((size_t)N_NODES * 4);
    int*       row_start = (int*)alloc((size_t)(N_NODES + 1) * 4);
    float*     dinv      = (float*)alloc((size_t)N_NODES * 4);
    int*       esrc      = (int*)alloc((size_t)N_EDGES * 4);
    int*       bsum      = (int*)alloc(512 * 4);
    _Float16*  tbl       = (_Float16*)alloc((size_t)(N_NODES + 1) * 64 * 2);  // gather table (+zero row)
    _Float16*  hbuf      = (_Float16*)alloc((size_t)N_LAYERS * N_NODES * 64 * 2);  // per-layer h
    _Float16*  Wt0       = (_Float16*)alloc((size_t)IN_FEAT * 64 * 2);
    _Float16*  Wtr       = (_Float16*)alloc((size_t)(N_LAYERS - 1) * 64 * 64 * 2);
    _Float16*  fcWt      = (_Float16*)alloc((size_t)48 * 64 * 2);

    hipMemsetAsync(count, 0, (size_t)N_NODES * 4, stream);

    int ge = (N_EDGES + 255) / 256;
    int gn = (N_NODES + 255) / 256;  // 391
    count_kernel<<<ge, 256, 0, stream>>>(dst, count);
    scan1_kernel<<<gn, 256, 0, stream>>>(count, row_start, bsum, dinv);
    scan2_kernel<<<1, 512, 0, stream>>>(bsum, gn);
    scan3_kernel<<<gn, 256, 0, stream>>>(row_start, bsum);
    fill_kernel<<<ge, 256, 0, stream>>>(src, dst, row_start, count, esrc);
    prep_w<<<(IN_FEAT * 64 + 255) / 256, 256, 0, stream>>>(W0, W_rest, fcW, Wt0, Wtr, fcWt, tbl);

    int g_gemm = (N_NODES + 127) / 128;  // 782
    int g_fc   = (N_NODES + 63) / 64;    // 1563
    int g_node = (N_NODES + 3) / 4;      // 25000

    const size_t HST = (size_t)N_NODES * 64;
    gemm_mfma<<<g_gemm, 256, 0, stream>>>(x, 1, IN_FEAT, Wt0, dinv, tbl, N_NODES);
    agg_kernel<<<g_node, 256, 0, stream>>>(tbl, row_start, esrc, dinv, b0, hbuf);
    for (int l = 1; l < N_LAYERS; l++) {
        gemm_mfma<<<g_gemm, 256, 0, stream>>>(hbuf + (size_t)(l - 1) * HST, 0, HIDDEN,
                                              Wtr + (size_t)(l - 1) * 4096, dinv, tbl, N_NODES);
        agg_kernel<<<g_node, 256, 0, stream>>>(tbl, row_start, esrc, dinv,
                                               b_rest + (size_t)(l - 1) * 64, hbuf + (size_t)l * HST);
    }
    fc_mfma<<<g_fc, 256, 0, stream>>>(hbuf, fcWt, fcb, out, N_NODES);
}

// Round 2
// 768.042 us; speedup vs baseline: 1.0748x; 1.0281x over previous
//
#include <hip/hip_runtime.h>
#include <math.h>

#define N_NODES 100000
#define N_EDGES 1600000
#define IN_FEAT 512
#define HIDDEN 64
#define N_CLASSES 40
#define N_LAYERS 6

typedef _Float16 v8h __attribute__((ext_vector_type(8)));
typedef _Float16 v4h __attribute__((ext_vector_type(4)));
typedef float v4f __attribute__((ext_vector_type(4)));

// ---------------- graph preprocessing ----------------

__global__ void count_kernel(const int* __restrict__ dst, int* __restrict__ count) {
    int e = blockIdx.x * blockDim.x + threadIdx.x;
    if (e < N_EDGES) atomicAdd(&count[dst[e]], 1);
}

// scan over counts; also emits dinv = rsqrt(deg+1) (merged former dinv_kernel)
__global__ void scan1_kernel(const int* __restrict__ count, int* __restrict__ row_start,
                             int* __restrict__ bsum, float* __restrict__ dinv) {
    __shared__ int sm[256];
    int t = threadIdx.x;
    int g = blockIdx.x * 256 + t;
    int v = (g < N_NODES) ? count[g] : 0;
    if (g < N_NODES) dinv[g] = rsqrtf((float)(v + 1));  // +1 self loop
    sm[t] = v;
    __syncthreads();
    int x = v;
    for (int off = 1; off < 256; off <<= 1) {
        int y = (t >= off) ? sm[t - off] : 0;
        __syncthreads();
        x += y;
        sm[t] = x;
        __syncthreads();
    }
    if (g < N_NODES) row_start[g] = x - v;
    if (t == 255) bsum[blockIdx.x] = x;
}

__global__ void scan2_kernel(int* __restrict__ bsum, int nb) {
    __shared__ int sm[512];
    int t = threadIdx.x;
    int v = (t < nb) ? bsum[t] : 0;
    sm[t] = v;
    __syncthreads();
    int x = v;
    for (int off = 1; off < 512; off <<= 1) {
        int y = (t >= off) ? sm[t - off] : 0;
        __syncthreads();
        x += y;
        sm[t] = x;
        __syncthreads();
    }
    if (t < nb) bsum[t] = x - v;
}

__global__ void scan3_kernel(int* __restrict__ row_start, const int* __restrict__ bsum) {
    int g = blockIdx.x * 256 + threadIdx.x;
    if (g < N_NODES) row_start[g] += bsum[blockIdx.x];
    if (g == 0) row_start[N_NODES] = N_EDGES;
}

// CSR fill: src index only (norm folded into table rows). Reuses count as the
// cursor via atomicSub -> no cursor buffer, no second memset.
__global__ void fill_kernel(const int* __restrict__ src, const int* __restrict__ dst,
                            const int* __restrict__ row_start, int* __restrict__ count,
                            int* __restrict__ esrc) {
    int e = blockIdx.x * blockDim.x + threadIdx.x;
    if (e < N_EDGES) {
        int s = src[e], d = dst[e];
        int old = atomicSub(&count[d], 1);
        esrc[row_start[d] + old - 1] = s;
    }
}

// ---------------- weight prep: fp32 -> f16 transposed; zero table row ----------------

__global__ void prep_w(const float* __restrict__ W0, const float* __restrict__ W_rest,
                       const float* __restrict__ fcW,
                       _Float16* __restrict__ Wt0, _Float16* __restrict__ Wtr,
                       _Float16* __restrict__ fcWt, _Float16* __restrict__ tbl) {
    int i = blockIdx.x * 256 + threadIdx.x;
    if (i < IN_FEAT * 64) {
        int k = i >> 6, n = i & 63;
        Wt0[n * IN_FEAT + k] = (_Float16)W0[i];
    }
    if (i < (N_LAYERS - 1) * 64 * 64) {
        int l = i >> 12, k = (i >> 6) & 63, n = i & 63;
        Wtr[l * 4096 + n * 64 + k] = (_Float16)W_rest[i];
    }
    if (i < 48 * 64) {  // fcWt[n][k], pad n 40..47 with 0
        int n = i >> 6, k = i & 63;
        fcWt[i] = (n < N_CLASSES) ? (_Float16)fcW[k * N_CLASSES + n] : (_Float16)0.f;
    }
    if (i < 64) tbl[(size_t)N_NODES * 64 + i] = (_Float16)0.f;  // zero row for masked lanes
}

// ---------------- MFMA f16 GEMM: C[M x 64] = dinv[row] * (A[M x K] @ W[K x 64]) ----------------
// M-tile 128, BK=64 (single barrier pair per 64 K), 4 waves. LDS rows padded to
// 72 f16 (144 B): frag b128 reads 2-way bank aliased = free (m136).

#define LDP2 72

__global__ __launch_bounds__(256) void gemm_mfma(const void* __restrict__ Ap, int a_fp32, int K,
                                                 const _Float16* __restrict__ Wt,
                                                 const float* __restrict__ dinv,
                                                 _Float16* __restrict__ C, int M) {
    __shared__ _Float16 As[128][LDP2];
    __shared__ _Float16 Ws[64][LDP2];
    int t = threadIdx.x;
    int lane = t & 63, w = t >> 6;
    int quad = lane >> 4, l15 = lane & 15;
    int m0 = blockIdx.x * 128;
    v4f acc[2][4];
    #pragma unroll
    for (int u = 0; u < 2; u++)
        #pragma unroll
        for (int n = 0; n < 4; n++) acc[u][n] = (v4f){0.f, 0.f, 0.f, 0.f};

    for (int k0 = 0; k0 < K; k0 += 64) {
        if (a_fp32) {
            const float* A = (const float*)Ap;
            #pragma unroll
            for (int i = 0; i < 8; i++) {
                int idx = t + i * 256;            // 0..2047: 128 rows x 16 float4-segs
                int r = idx >> 4, seg = idx & 15;
                int gr = m0 + r;
                float4 v = make_float4(0.f, 0.f, 0.f, 0.f);
                if (gr < M) v = *(const float4*)(A + (size_t)gr * K + k0 + seg * 4);
                v4h h = {(_Float16)v.x, (_Float16)v.y, (_Float16)v.z, (_Float16)v.w};
                *(v4h*)&As[r][seg * 4] = h;
            }
        } else {
            const _Float16* A = (const _Float16*)Ap;
            #pragma unroll
            for (int i = 0; i < 4; i++) {
                int idx = t + i * 256;            // 0..1023: 128 rows x 8 uint4-segs
                int r = idx >> 3, seg = idx & 7;
                int gr = m0 + r;
                uint4 v = make_uint4(0u, 0u, 0u, 0u);
                if (gr < M) v = *(const uint4*)(A + (size_t)gr * K + k0 + seg * 8);
                *(uint4*)&As[r][seg * 8] = v;
            }
        }
        #pragma unroll
        for (int i = 0; i < 2; i++) {
            int idx = t + i * 256;                // 0..511: 64 rows x 8 uint4-segs
            int r = idx >> 3, seg = idx & 7;
            *(uint4*)&Ws[r][seg * 8] = *(const uint4*)(Wt + (size_t)r * K + k0 + seg * 8);
        }
        __syncthreads();
        #pragma unroll
        for (int kk = 0; kk < 2; kk++) {
            v8h a0 = *(v8h*)&As[w * 32 + l15][kk * 32 + quad * 8];
            v8h a1 = *(v8h*)&As[w * 32 + 16 + l15][kk * 32 + quad * 8];
            #pragma unroll
            for (int n = 0; n < 4; n++) {
                v8h b = *(v8h*)&Ws[n * 16 + l15][kk * 32 + quad * 8];
                acc[0][n] = __builtin_amdgcn_mfma_f32_16x16x32_f16(a0, b, acc[0][n], 0, 0, 0);
                acc[1][n] = __builtin_amdgcn_mfma_f32_16x16x32_f16(a1, b, acc[1][n], 0, 0, 0);
            }
        }
        __syncthreads();
    }
    #pragma unroll
    for (int u = 0; u < 2; u++)
        #pragma unroll
        for (int r = 0; r < 4; r++) {
            int gr = m0 + w * 32 + u * 16 + quad * 4 + r;
            if (gr < M) {
                float di = dinv[gr];  // broadcast across the 16 l15 lanes
                #pragma unroll
                for (int n = 0; n < 4; n++)
                    C[(size_t)gr * 64 + n * 16 + l15] = (_Float16)(acc[u][n][r] * di);
            }
        }
}

// ---------------- aggregation + bias + relu ----------------
// One wave per node. Lane = g*8+j: group g handles one edge per round, lane
// loads a b128 (8 f16 feats) -> 8 edges per gather instruction.
//
// Latency restructure (this round): the node's edge indices are CONTIGUOUS in
// CSR, so one coalesced 64-lane dword load fetches up to 64 src indices; each
// round's per-group index is recovered in-register via __shfl (ds_bpermute).
// This removes the per-round dependent esrc load and lets gathers issue in
// batches of 4-in-flight instead of 1 serial per round. Table rows are
// pre-scaled by dinv[src] (GEMM epilogue): edges are weightless adds; OOB
// lanes gather the zero row (index N_NODES, L1-broadcast). Self-loop =
// group-0 init. Final scale by dinv[node]. JK max deferred to fc.

__global__ __launch_bounds__(256) void agg_kernel(const _Float16* __restrict__ tbl,
                                                  const int* __restrict__ row_start,
                                                  const int* __restrict__ esrc,
                                                  const float* __restrict__ dinv,
                                                  const float* __restrict__ bias,
                                                  _Float16* __restrict__ h_out) {
    int wid = (blockIdx.x * blockDim.x + threadIdx.x) >> 6;
    if (wid >= N_NODES) return;
    int node = __builtin_amdgcn_readfirstlane(wid);
    int lane = threadIdx.x & 63;
    int g = lane >> 3, j = lane & 7;
    const v8h* t8 = (const v8h*)tbl;
    float di = dinv[node];
    int e0 = row_start[node], e1 = row_start[node + 1];

    float a[8];
    // self loop: table row already dinv[node]-scaled; keep only in group 0
    {
        v8h v = t8[(size_t)node * 8 + j];
        #pragma unroll
        for (int i = 0; i < 8; i++) a[i] = (g == 0) ? (float)v[i] : 0.f;
    }

    for (int chunk = e0; chunk < e1; chunk += 64) {
        int idx = chunk + lane;
        int myc = (idx < e1) ? esrc[idx] : N_NODES;  // one coalesced load, 64 edges
        int rem = e1 - chunk;                        // > 0 (uniform across wave)
        #pragma unroll
        for (int b = 0; b < 2; b++) {                // 2 batches x 4 rounds
            int base = b * 32;
            if (base < rem) {                        // uniform branch
                int nrb = min(4, (rem - base + 7) >> 3);
                v8h vv[4];
                #pragma unroll
                for (int r = 0; r < 4; r++) {
                    if (r < nrb) {                   // uniform
                        int c = __shfl(myc, base + r * 8 + g, 64);
                        vv[r] = t8[(size_t)c * 8 + j];   // 4 gathers in flight
                    }
                }
                #pragma unroll
                for (int r = 0; r < 4; r++) {
                    if (r < nrb) {
                        #pragma unroll
                        for (int i = 0; i < 8; i++) a[i] += (float)vv[r][i];
                    }
                }
            }
        }
    }

    // combine the 8 lane-groups (xor over g bits 3,4,5)
    #pragma unroll
    for (int i = 0; i < 8; i++) {
        a[i] += __shfl_xor(a[i], 8, 64);
        a[i] += __shfl_xor(a[i], 16, 64);
        a[i] += __shfl_xor(a[i], 32, 64);
    }
    if (g == 0) {
        const float4* b4 = (const float4*)bias;
        float4 b0 = b4[j * 2], b1 = b4[j * 2 + 1];
        float bb[8] = {b0.x, b0.y, b0.z, b0.w, b1.x, b1.y, b1.z, b1.w};
        v8h hv;
        #pragma unroll
        for (int i = 0; i < 8; i++) hv[i] = (_Float16)fmaxf(a[i] * di + bb[i], 0.0f);
        ((v8h*)h_out)[(size_t)node * 8 + j] = hv;
    }
}

// ---------------- FC + log_softmax via MFMA; JK max fused into A-stage ----------------
// block 256 = 4 waves, M-tile 64 rows; N=48 (40 padded); K=64, single stage.

__global__ __launch_bounds__(256) void fc_mfma(const _Float16* __restrict__ hb,
                                               const _Float16* __restrict__ fcWt,
                                               const float* __restrict__ fcb,
                                               float* __restrict__ out, int M) {
    __shared__ _Float16 As[64][LDP2];
    __shared__ _Float16 Ws[48][LDP2];
    __shared__ float bs[48];
    int t = threadIdx.x;
    int lane = t & 63, w = t >> 6;
    int quad = lane >> 4, l15 = lane & 15;
    int m0 = blockIdx.x * 64;
    const size_t HST = (size_t)N_NODES * 64;

    if (t < 48) bs[t] = (t < N_CLASSES) ? fcb[t] : 0.0f;

    // A-stage with 6-layer elementwise max (values are post-relu >= 0)
    #pragma unroll
    for (int i = 0; i < 2; i++) {
        int idx = t + i * 256;                    // 0..511: 64 rows x 8 v8h-segs
        int r = idx >> 3, seg = idx & 7;
        int gr = m0 + r;
        v8h m = (v8h)(_Float16)0.f;
        if (gr < M) {
            size_t off = (size_t)gr * 64 + seg * 8;
            m = *(const v8h*)(hb + off);
            #pragma unroll
            for (int l = 1; l < N_LAYERS; l++) {
                v8h u = *(const v8h*)(hb + l * HST + off);
                #pragma unroll
                for (int k = 0; k < 8; k++) m[k] = (u[k] > m[k]) ? u[k] : m[k];
            }
        }
        *(v8h*)&As[r][seg * 8] = m;
    }
    #pragma unroll
    for (int i = 0; i < 2; i++) {
        int idx = t + i * 256;                    // 48 rows x 8 segs = 384
        if (idx < 384) {
            int r = idx >> 3, seg = idx & 7;
            *(uint4*)&Ws[r][seg * 8] = *(const uint4*)(fcWt + (size_t)r * 64 + seg * 8);
        }
    }
    __syncthreads();

    v4f acc[3];
    #pragma unroll
    for (int n = 0; n < 3; n++) acc[n] = (v4f){0.f, 0.f, 0.f, 0.f};
    #pragma unroll
    for (int kk = 0; kk < 2; kk++) {
        v8h a = *(v8h*)&As[w * 16 + l15][kk * 32 + quad * 8];
        #pragma unroll
        for (int n = 0; n < 3; n++) {
            v8h b = *(v8h*)&Ws[n * 16 + l15][kk * 32 + quad * 8];
            acc[n] = __builtin_amdgcn_mfma_f32_16x16x32_f16(a, b, acc[n], 0, 0, 0);
        }
    }

    float val[3][4];
    #pragma unroll
    for (int n = 0; n < 3; n++) {
        int col = n * 16 + l15;
        #pragma unroll
        for (int r = 0; r < 4; r++)
            val[n][r] = (col < N_CLASSES) ? acc[n][r] + bs[col] : -INFINITY;
    }
    #pragma unroll
    for (int r = 0; r < 4; r++) {
        float m = fmaxf(fmaxf(val[0][r], val[1][r]), val[2][r]);
        #pragma unroll
        for (int off = 8; off; off >>= 1) m = fmaxf(m, __shfl_xor(m, off, 64));
        float s = 0.f;
        #pragma unroll
        for (int n = 0; n < 3; n++)
            if (n * 16 + l15 < N_CLASSES) s += expf(val[n][r] - m);
        #pragma unroll
        for (int off = 8; off; off >>= 1) s += __shfl_xor(s, off, 64);
        float lse = m + logf(s);
        int gr = m0 + w * 16 + quad * 4 + r;
        if (gr < M) {
            #pragma unroll
            for (int n = 0; n < 3; n++) {
                int col = n * 16 + l15;
                if (col < N_CLASSES) out[(size_t)gr * N_CLASSES + col] = val[n][r] - lse;
            }
        }
    }
}

// ---------------- launch ----------------

extern "C" void kernel_launch(void* const* d_in, const int* in_sizes, int n_in,
                              void* d_out, int out_size, void* d_ws, size_t ws_size,
                              hipStream_t stream) {
    const float* x      = (const float*)d_in[0];
    const int*   ei     = (const int*)d_in[1];
    const float* W0     = (const float*)d_in[2];
    const float* b0     = (const float*)d_in[3];
    const float* W_rest = (const float*)d_in[4];
    const float* b_rest = (const float*)d_in[5];
    const float* fcW    = (const float*)d_in[6];
    const float* fcb    = (const float*)d_in[7];
    float* out = (float*)d_out;

    const int* src = ei;
    const int* dst = ei + N_EDGES;

    char* w = (char*)d_ws;
    auto alloc = [&](size_t bytes) -> void* {
        void* p = (void*)w;
        w += (bytes + 255) / 256 * 256;
        return p;
    };
    int*       count     = (int*)alloc((size_t)N_NODES * 4);
    int*       row_start = (int*)alloc((size_t)(N_NODES + 1) * 4);
    float*     dinv      = (float*)alloc((size_t)N_NODES * 4);
    int*       esrc      = (int*)alloc((size_t)N_EDGES * 4);
    int*       bsum      = (int*)alloc(512 * 4);
    _Float16*  tbl       = (_Float16*)alloc((size_t)(N_NODES + 1) * 64 * 2);  // gather table (+zero row)
    _Float16*  hbuf      = (_Float16*)alloc((size_t)N_LAYERS * N_NODES * 64 * 2);  // per-layer h
    _Float16*  Wt0       = (_Float16*)alloc((size_t)IN_FEAT * 64 * 2);
    _Float16*  Wtr       = (_Float16*)alloc((size_t)(N_LAYERS - 1) * 64 * 64 * 2);
    _Float16*  fcWt      = (_Float16*)alloc((size_t)48 * 64 * 2);

    hipMemsetAsync(count, 0, (size_t)N_NODES * 4, stream);

    int ge = (N_EDGES + 255) / 256;
    int gn = (N_NODES + 255) / 256;  // 391
    count_kernel<<<ge, 256, 0, stream>>>(dst, count);
    scan1_kernel<<<gn, 256, 0, stream>>>(count, row_start, bsum, dinv);
    scan2_kernel<<<1, 512, 0, stream>>>(bsum, gn);
    scan3_kernel<<<gn, 256, 0, stream>>>(row_start, bsum);
    fill_kernel<<<ge, 256, 0, stream>>>(src, dst, row_start, count, esrc);
    prep_w<<<(IN_FEAT * 64 + 255) / 256, 256, 0, stream>>>(W0, W_rest, fcW, Wt0, Wtr, fcWt, tbl);

    int g_gemm = (N_NODES + 127) / 128;  // 782
    int g_fc   = (N_NODES + 63) / 64;    // 1563
    int g_node = (N_NODES + 3) / 4;      // 25000

    const size_t HST = (size_t)N_NODES * 64;
    gemm_mfma<<<g_gemm, 256, 0, stream>>>(x, 1, IN_FEAT, Wt0, dinv, tbl, N_NODES);
    agg_kernel<<<g_node, 256, 0, stream>>>(tbl, row_start, esrc, dinv, b0, hbuf);
    for (int l = 1; l < N_LAYERS; l++) {
        gemm_mfma<<<g_gemm, 256, 0, stream>>>(hbuf + (size_t)(l - 1) * HST, 0, HIDDEN,
                                              Wtr + (size_t)(l - 1) * 4096, dinv, tbl, N_NODES);
        agg_kernel<<<g_node, 256, 0, stream>>>(tbl, row_start, esrc, dinv,
                                               b_rest + (size_t)(l - 1) * 64, hbuf + (size_t)l * HST);
    }
    fc_mfma<<<g_fc, 256, 0, stream>>>(hbuf, fcWt, fcb, out, N_NODES);
}